// Round 10
// baseline (419.060 us; speedup 1.0000x reference)
//
#include <hip/hip_runtime.h>

// ---------------------------------------------------------------------------
// PriceGeometryEncoder on MI355X — round 10.  THREE dispatches:
//   prep  : weight transposes + zero pooled/qkmax/done
//   trunk : embed + 3 MLP chains + QKV, per-64-token block; all weights
//           sequenced through one 32KB LDS buffer; feats never leaves LDS.
//   attn  : flash attention, 2048 blocks x 64 q (8 blocks/CU), 64-key LDS
//           ring with raw s_barrier + lgkmcnt only (loads survive barriers),
//           static-max softmax, ones-MFMA lsum; LAST block computes the head
//           (mean-pool commutes: out = (mean_t(o) @ Wo + bo) @ Wout + bout).
// ---------------------------------------------------------------------------

typedef __attribute__((ext_vector_type(4)))  float f32x4;
typedef __attribute__((ext_vector_type(4)))  short short4v;
typedef __attribute__((ext_vector_type(8)))  short short8v;

static __device__ __forceinline__ unsigned short f2b(float f) {
    unsigned int u = __builtin_bit_cast(unsigned int, f);
    u += 0x7fffu + ((u >> 16) & 1u);       // round-to-nearest-even
    return (unsigned short)(u >> 16);
}

static __device__ __forceinline__ unsigned int cvtpk_bf16(float a, float b) {
    unsigned int r;
    asm volatile("v_cvt_pk_bf16_f32 %0, %1, %2" : "=v"(r) : "v"(a), "v"(b));
    return r;
}

// ---------------------------------------------------------------------------
// K0: blocks 0..47: Wqkv [128][384] f32 -> [384][128] bf16 via 32x32 tiles.
//     blocks 48+ : small weight transposes + zero pooled/qkmax/done.
// ---------------------------------------------------------------------------
__global__ __launch_bounds__(256) void prep_kernel(
    const float* Wqkv, const float* Wc1, const float* Wc2, const float* Wv1,
    const float* Wv2, const float* Ws1, const float* Ws2,
    unsigned short* wqkvt, unsigned short* wc1t, unsigned short* wc2t,
    unsigned short* wv1t, unsigned short* wv2t, unsigned short* ws1t,
    unsigned short* ws2t, float* pooled, float* qkmax, unsigned int* done)
{
    int tid = threadIdx.x;
    if (blockIdx.x < 48) {
        __shared__ float tile[32][33];
        int bidn = blockIdx.x % 12, bidk = blockIdx.x / 12;
        int n0 = bidn * 32, k0 = bidk * 32;
        {
            int r = tid >> 3, cq = tid & 7;
            float4 v = *(const float4*)(Wqkv + (size_t)(k0 + r) * 384 + n0 + cq * 4);
            tile[r][cq*4+0] = v.x; tile[r][cq*4+1] = v.y;
            tile[r][cq*4+2] = v.z; tile[r][cq*4+3] = v.w;
        }
        __syncthreads();
        {
            int nr = tid >> 3, kq = tid & 7;
            union { unsigned short us[4]; short4v v; } pk;
#pragma unroll
            for (int j = 0; j < 4; ++j) pk.us[j] = f2b(tile[kq*4+j][nr]);
            *(short4v*)(wqkvt + (size_t)(n0 + nr) * 128 + k0 + kq * 4) = pk.v;
        }
        return;
    }
    int idx = (blockIdx.x - 48) * 256 + tid;
    if (idx < 8192)  { int n = idx >> 6, kk = idx & 63;  wc1t[idx] = f2b(Wc1[kk*128 + n]); return; }
    idx -= 8192;
    if (idx < 4096)  { int n = idx >> 7, kk = idx & 127; wc2t[idx] = f2b(Wc2[kk*32  + n]); return; }
    idx -= 4096;
    if (idx < 4096)  { int n = idx >> 6, kk = idx & 63;  wv1t[idx] = f2b(Wv1[kk*64  + n]); return; }
    idx -= 4096;
    if (idx < 1024)  { int n = idx >> 6, kk = idx & 63;  wv2t[idx] = f2b(Wv2[kk*16  + n]); return; }
    idx -= 1024;
    if (idx < 4096)  { int n = idx >> 6, kk = idx & 63;  ws1t[idx] = f2b(Ws1[kk*64  + n]); return; }
    idx -= 4096;
    if (idx < 1024)  { int n = idx >> 6, kk = idx & 63;  ws2t[idx] = f2b(Ws2[kk*16  + n]); return; }
    idx -= 1024;
    if (idx < 2048)  { pooled[idx] = 0.f; return; }
    idx -= 2048;
    if (idx < 128)   { qkmax[idx] = 0.f; return; }
    idx -= 128;
    if (idx == 0)    done[0] = 0u;
}

// ---------------------------------------------------------------------------
// Stage weight [N][K] bf16 global -> LDS rows K*2 bytes, 16B-slot XOR swizzle.
// ---------------------------------------------------------------------------
template<int N, int K>
static __device__ __forceinline__ void stage_w(
    const unsigned short* __restrict__ wt, char* Bs, int tid)
{
    constexpr int SL = K / 8;
    for (int c = tid; c < N * SL; c += 256) {
        int n = c / SL, s = c % SL;
        short8v v = *(const short8v*)(wt + n * K + s * 8);
        *(short8v*)(Bs + n * (K * 2) + ((s ^ (n & (SL - 1))) << 4)) = v;
    }
}

// ---------------------------------------------------------------------------
// Wave GEMM: 16 tokens x N.  A from 256B-row LDS tile (mask 15), B from
// staged LDS weights (rows K*2 B, mask K/8-1).  acc returned.
// ---------------------------------------------------------------------------
template<int N, int K>
static __device__ __forceinline__ void wave_gemm_l(
    const char* As, const char* Bs, int w, int lane, f32x4* acc)
{
    constexpr int BSL = K / 8, NT = N / 16, KS = K / 32;
    int l15 = lane & 15, hi4 = lane >> 4;
#pragma unroll
    for (int nt = 0; nt < NT; ++nt)
#pragma unroll
        for (int r = 0; r < 4; ++r) acc[nt][r] = 0.f;
#pragma unroll
    for (int ks = 0; ks < KS; ++ks) {
        int slot = ks * 4 + hi4;
        int m = w * 16 + l15;
        short8v af = *(const short8v*)(As + m * 256 + ((slot ^ (m & 15)) << 4));
#pragma unroll
        for (int nt = 0; nt < NT; ++nt) {
            int n = nt * 16 + l15;
            short8v bf = *(const short8v*)(Bs + n * (K * 2) + ((slot ^ (n & (BSL - 1))) << 4));
            acc[nt] = __builtin_amdgcn_mfma_f32_16x16x32_bf16(af, bf, acc[nt], 0, 0, 0);
        }
    }
}

template<int N, int K, bool RELU>
static __device__ __forceinline__ void mlp_gemm(
    const char* As, const char* Bs, const float* __restrict__ bias,
    char* dst, int ocol, int w, int lane)
{
    f32x4 acc[N / 16];
    wave_gemm_l<N, K>(As, Bs, w, lane, acc);
    int l15 = lane & 15, hi4 = lane >> 4;
#pragma unroll
    for (int nt = 0; nt < N / 16; ++nt) {
        int n = nt * 16 + l15;
        float bv = bias[n];
#pragma unroll
        for (int r = 0; r < 4; ++r) {
            int m = w * 16 + hi4 * 4 + r;
            float v = acc[nt][r] + bv;
            if (RELU) v = fmaxf(v, 0.f);
            int col = ocol + n;
            *(unsigned short*)(dst + m * 256 + (((col >> 3) ^ (m & 15)) << 4) + (col & 7) * 2) = f2b(v);
        }
    }
}

// q/k epilogue: scale, per-head amax (atomicMax), bounce via Ht, coalesced
// b128 stores to [bh][t][32].  Contains ONE block barrier.
static __device__ __forceinline__ void epi_qk64(
    f32x4* acc, const float* __restrict__ bqkv, int boff, float scale,
    unsigned short* __restrict__ og, float* qkmaxp,
    int b, int tp0, int w, int lane, char* Ht, int tid)
{
    int l15 = lane & 15, hi4 = lane >> 4;
    float amax[4] = {0.f, 0.f, 0.f, 0.f};
#pragma unroll
    for (int nt = 0; nt < 8; ++nt) {
        int n = nt * 16 + l15;
        float bv = bqkv[boff + n];
#pragma unroll
        for (int r = 0; r < 4; ++r) {
            int m = w * 16 + hi4 * 4 + r;
            float v = (acc[nt][r] + bv) * scale;
            amax[nt >> 1] = fmaxf(amax[nt >> 1], fabsf(v));
            *(unsigned short*)(Ht + m * 256 + (((n >> 3) ^ (m & 15)) << 4) + (n & 7) * 2) = f2b(v);
        }
    }
#pragma unroll
    for (int g = 0; g < 4; ++g) {
        float mv = amax[g];
        mv = fmaxf(mv, __shfl_xor(mv, 1));  mv = fmaxf(mv, __shfl_xor(mv, 2));
        mv = fmaxf(mv, __shfl_xor(mv, 4));  mv = fmaxf(mv, __shfl_xor(mv, 8));
        mv = fmaxf(mv, __shfl_xor(mv, 16)); mv = fmaxf(mv, __shfl_xor(mv, 32));
        if (lane == 0)
            atomicMax((int*)(qkmaxp + b * 4 + g), __float_as_int(mv));
    }
    __syncthreads();
#pragma unroll
    for (int it = 0; it < 4; ++it) {
        int ch = it * 256 + tid;
        int m = ch >> 4, c = ch & 15;
        short8v vv = *(const short8v*)(Ht + m * 256 + ((c ^ (m & 15)) << 4));
        int h = c >> 2, dq = c & 3;
        *(short8v*)(og + ((size_t)(b * 4 + h) * 2048 + tp0 + m) * 32 + dq * 8) = vv;
    }
}

// ---------------------------------------------------------------------------
// K1: trunk — embed + 3 MLP chains + QKV for 64 tokens/block, 4 waves x 16.
// Weights sequenced through one 32KB Bw buffer.  LDS 65.3KB -> 2 blocks/CU,
// all 512 blocks co-resident.  q/k -> [bh][t][32]; v -> kappa tiles.
// ---------------------------------------------------------------------------
__global__ __launch_bounds__(256) void trunk_kernel(
    const float* __restrict__ ohlc, const float* __restrict__ Wp, const float* __restrict__ bp,
    const unsigned short* __restrict__ wc1t, const float* __restrict__ bc1,
    const unsigned short* __restrict__ wc2t, const float* __restrict__ bc2,
    const unsigned short* __restrict__ wv1t, const float* __restrict__ bv1,
    const unsigned short* __restrict__ wv2t, const float* __restrict__ bv2,
    const unsigned short* __restrict__ ws1t, const float* __restrict__ bs1,
    const unsigned short* __restrict__ ws2t, const float* __restrict__ bs2,
    const unsigned short* __restrict__ wqkvt, const float* __restrict__ bqkv,
    unsigned short* __restrict__ qg, unsigned short* __restrict__ kg,
    unsigned short* __restrict__ vt2, float* __restrict__ qkmax)
{
    __shared__ float wp[256];
    __shared__ float bpl[64];
    __shared__ char Ft[64 * 256];    // feats tile, 256B rows, mask-15 swizzle
    __shared__ char Ht[64 * 256];    // hidden / epilogue bounce
    __shared__ char Bw[32768];       // sequenced weight buffer

    int tid = threadIdx.x;
    int m0 = blockIdx.x * 64;
    int b = m0 >> 11, tp0 = m0 & 2047;
    wp[tid] = Wp[tid];
    if (tid < 64) bpl[tid] = bp[tid];
    stage_w<128, 64>(wc1t, Bw, tid);
    stage_w< 32, 128>(wc2t, Bw + 16384, tid);
    __syncthreads();

    {   // embed -> Ft cols 0..63 (wave-local rows)
        int tok = tid >> 2, jq = tid & 3;
        float4 ov = ((const float4*)ohlc)[m0 + tok];
#pragma unroll
        for (int c = 0; c < 2; ++c) {
            int sl = jq * 2 + c;
            union { unsigned short us[8]; short8v v; } pk;
#pragma unroll
            for (int jj = 0; jj < 8; ++jj) {
                int j = sl * 8 + jj;
                float e = bpl[j] + ov.x * wp[j] + ov.y * wp[64 + j]
                                 + ov.z * wp[128 + j] + ov.w * wp[192 + j];
                pk.us[jj] = f2b(e);
            }
            *(short8v*)(Ft + tok * 256 + ((sl ^ (tok & 15)) << 4)) = pk.v;
        }
    }

    int lane = tid & 63, w = tid >> 6;
    mlp_gemm<128, 64, true >(Ft, Bw,         bc1, Ht, 0,  w, lane);
    mlp_gemm< 32, 128, false>(Ht, Bw + 16384, bc2, Ft, 64, w, lane);
    __syncthreads();
    stage_w<64, 64>(wv1t, Bw, tid);
    stage_w<16, 64>(wv2t, Bw + 8192, tid);
    stage_w<64, 64>(ws1t, Bw + 10240, tid);
    stage_w<16, 64>(ws2t, Bw + 18432, tid);
    __syncthreads();
    mlp_gemm<64, 64, true >(Ft, Bw,         bv1, Ht, 0,   w, lane);
    mlp_gemm<16, 64, false>(Ht, Bw + 8192,  bv2, Ft, 96,  w, lane);
    mlp_gemm<64, 64, true >(Ft, Bw + 10240, bs1, Ht, 0,   w, lane);
    mlp_gemm<16, 64, false>(Ht, Bw + 18432, bs2, Ft, 112, w, lane);
    __syncthreads();

    const float QSCALE = 1.4426950408889634f * 0.17677669529663687f; // log2e/sqrt(32)
    stage_w<128, 128>(wqkvt, Bw, tid);
    __syncthreads();
    {
        f32x4 aq[8];
        wave_gemm_l<128, 128>(Ft, Bw, w, lane, aq);
        epi_qk64(aq, bqkv, 0, QSCALE, qg, qkmax, b, tp0, w, lane, Ht, tid);
    }
    stage_w<128, 128>(wqkvt + 16384, Bw, tid);
    __syncthreads();
    {
        f32x4 ak[8];
        wave_gemm_l<128, 128>(Ft, Bw, w, lane, ak);
        epi_qk64(ak, bqkv, 128, 1.0f, kg, qkmax + 64, b, tp0, w, lane, Ht, tid);
    }
    stage_w<128, 128>(wqkvt + 32768, Bw, tid);
    __syncthreads();
    {
        f32x4 av[8];
        wave_gemm_l<128, 128>(Ft, Bw, w, lane, av);
        int l15 = lane & 15, hi4 = lane >> 4;
        int g32 = (tp0 >> 5) + (w >> 1);
        int kb = hi4 * 8 + (w & 1) * 4;
#pragma unroll
        for (int nt = 0; nt < 8; ++nt) {
            int n = nt * 16 + l15;
            float bv = bqkv[256 + n];
            int h = n >> 5, dh = n & 31;
            uint2 pk;
            pk.x = cvtpk_bf16(av[nt][0] + bv, av[nt][1] + bv);
            pk.y = cvtpk_bf16(av[nt][2] + bv, av[nt][3] + bv);
            *(uint2*)(vt2 + (size_t)(b * 4 + h) * 65536 + (size_t)g32 * 1024
                          + dh * 32 + kb) = pk;
        }
    }
}

// ---------------------------------------------------------------------------
// K2: flash attention — 2048 blocks x 64 q (4 waves x 16 q), 8 blocks/CU.
// 64-key phases in a 2x8KB LDS ring; raw s_barrier + lgkmcnt(0) only (K/V
// prefetch loads stay in flight across barriers).  Static-max softmax
// (NEGM4 C-init); lsum via ones-MFMA.  Last block computes the head.
// ---------------------------------------------------------------------------
__global__ __launch_bounds__(256) void attn_kernel(
    const unsigned short* __restrict__ qg, const unsigned short* __restrict__ kg,
    const unsigned short* __restrict__ vt2, const float* __restrict__ qkmax,
    float* __restrict__ pooled, unsigned int* __restrict__ done,
    const float* __restrict__ Wo, const float* __restrict__ bo,
    const float* __restrict__ Wout, const float* __restrict__ bout,
    float* __restrict__ out)
{
    __shared__ char Kv[2][8192];   // per 64-key group: [K0 2K | V0 2K | K1 2K | V1 2K]
    __shared__ int lastFlag;

    int tid = threadIdx.x, bid = blockIdx.x;
    int bh = bid & 63, qc = bid >> 6;          // qc 0..31
    int b = bh >> 2;
    int lane = tid & 63, w = tid >> 6;
    int l15 = lane & 15, h = (lane >> 4) & 3;
    int q0 = qc * 64 + w * 16;

    const char* qp = (const char*)qg + ((size_t)bh * 2048 + q0) * 64 + l15 * 64 + h * 16;
    short8v Qf = *(const short8v*)qp;

    float negM0 = -(32.0f * qkmax[bh] * qkmax[64 + bh]);
    f32x4 NEGM4 = {negM0, negM0, negM0, negM0};

    f32x4 accO0, accO1, lacc;
#pragma unroll
    for (int r = 0; r < 4; ++r) { accO0[r] = 0.f; accO1[r] = 0.f; lacc[r] = 0.f; }

    short8v ONES;
    {
        union { unsigned short us[8]; short8v v; } u;
#pragma unroll
        for (int j = 0; j < 8; ++j) u.us[j] = 0x3F80;      // bf16 1.0
        ONES = u.v;
    }

    const char* gk = (const char*)kg  + (size_t)bh * 131072;
    const char* gv = (const char*)vt2 + (size_t)bh * 131072;
    bool isK = tid < 128;
    int t128 = tid & 127;
    const char* gsrc = (isK ? gk : gv) + t128 * 16;
    int ldst = (isK ? 0 : 2048) + t128 * 16;
    int foff = l15 * 64 + h * 16;

    auto compute = [&](const char* bufp) {
        short8v Ka = *(const short8v*)(bufp + foff);
        short8v Kb = *(const short8v*)(bufp + 1024 + foff);
        short8v Va = *(const short8v*)(bufp + 2048 + foff);
        short8v Vb = *(const short8v*)(bufp + 3072 + foff);
        __builtin_amdgcn_s_setprio(1);
        f32x4 s0 = __builtin_amdgcn_mfma_f32_16x16x32_bf16(Ka, Qf, NEGM4, 0, 0, 0);
        f32x4 s1 = __builtin_amdgcn_mfma_f32_16x16x32_bf16(Kb, Qf, NEGM4, 0, 0, 0);
        float p00 = __builtin_amdgcn_exp2f(s0[0]);
        float p01 = __builtin_amdgcn_exp2f(s0[1]);
        float p02 = __builtin_amdgcn_exp2f(s0[2]);
        float p03 = __builtin_amdgcn_exp2f(s0[3]);
        float p10 = __builtin_amdgcn_exp2f(s1[0]);
        float p11 = __builtin_amdgcn_exp2f(s1[1]);
        float p12 = __builtin_amdgcn_exp2f(s1[2]);
        float p13 = __builtin_amdgcn_exp2f(s1[3]);
        union { unsigned int u[4]; short8v v; } pk;
        pk.u[0] = cvtpk_bf16(p00, p01);
        pk.u[1] = cvtpk_bf16(p02, p03);
        pk.u[2] = cvtpk_bf16(p10, p11);
        pk.u[3] = cvtpk_bf16(p12, p13);
        lacc  = __builtin_amdgcn_mfma_f32_16x16x32_bf16(ONES, pk.v, lacc, 0, 0, 0);
        accO0 = __builtin_amdgcn_mfma_f32_16x16x32_bf16(Va,   pk.v, accO0, 0, 0, 0);
        accO1 = __builtin_amdgcn_mfma_f32_16x16x32_bf16(Vb,   pk.v, accO1, 0, 0, 0);
        __builtin_amdgcn_s_setprio(0);
    };

    // prologue: stage group 0; prefetch group 1
    short8v Ra0 = *(const short8v*)(gsrc);
    short8v Ra1 = *(const short8v*)(gsrc + 2048);
    *(short8v*)(Kv[0] + ldst) = Ra0;
    *(short8v*)(Kv[0] + 4096 + ldst) = Ra1;
    short8v Rb0 = *(const short8v*)(gsrc + 4096);
    short8v Rb1 = *(const short8v*)(gsrc + 6144);
    asm volatile("s_waitcnt lgkmcnt(0)" ::: "memory");
    __builtin_amdgcn_s_barrier();
    __builtin_amdgcn_sched_barrier(0);

    const char* gp = gsrc + 8192;
#pragma unroll 1
    for (int g = 0; g < 30; g += 2) {
        *(short8v*)(Kv[1] + ldst) = Rb0;
        *(short8v*)(Kv[1] + 4096 + ldst) = Rb1;
        Ra0 = *(const short8v*)(gp);
        Ra1 = *(const short8v*)(gp + 2048);
        compute(Kv[0]); compute(Kv[0] + 4096);
        asm volatile("s_waitcnt lgkmcnt(0)" ::: "memory");
        __builtin_amdgcn_s_barrier();
        __builtin_amdgcn_sched_barrier(0);
        *(short8v*)(Kv[0] + ldst) = Ra0;
        *(short8v*)(Kv[0] + 4096 + ldst) = Ra1;
        Rb0 = *(const short8v*)(gp + 4096);
        Rb1 = *(const short8v*)(gp + 6144);
        gp += 8192;
        compute(Kv[1]); compute(Kv[1] + 4096);
        asm volatile("s_waitcnt lgkmcnt(0)" ::: "memory");
        __builtin_amdgcn_s_barrier();
        __builtin_amdgcn_sched_barrier(0);
    }
    // tail: buf0 = group 30, Rb = group 31
    *(short8v*)(Kv[1] + ldst) = Rb0;
    *(short8v*)(Kv[1] + 4096 + ldst) = Rb1;
    compute(Kv[0]); compute(Kv[0] + 4096);
    asm volatile("s_waitcnt lgkmcnt(0)" ::: "memory");
    __builtin_amdgcn_s_barrier();
    __builtin_amdgcn_sched_barrier(0);
    compute(Kv[1]); compute(Kv[1] + 4096);

    // normalize per q (lane-local lsum), reduce over 16 q's, add column sums
    float inv = 1.0f / (lacc[0] + 1e-30f);
#pragma unroll
    for (int d = 0; d < 2; ++d)
#pragma unroll
        for (int r = 0; r < 4; ++r) {
            float v = (d ? accO1[r] : accO0[r]) * inv;
            v += __shfl_xor(v, 1); v += __shfl_xor(v, 2);
            v += __shfl_xor(v, 4); v += __shfl_xor(v, 8);
            if (l15 == 0) {
                int dh = d * 16 + h * 4 + r;
                atomicAdd(pooled + b * 128 + (bh & 3) * 32 + dh, v);
            }
        }

    // ---- last block computes the head ----
    __threadfence();
    __syncthreads();
    if (tid == 0) lastFlag = (atomicAdd(done, 1u) == 2047u) ? 1 : 0;
    __syncthreads();
    if (lastFlag) {
        float* plbuf = (float*)&Kv[0][0];
        float* midb  = plbuf + 2048;
        for (int i = tid; i < 2048; i += 256)
            plbuf[i] = __hip_atomic_load(pooled + i, __ATOMIC_RELAXED,
                                         __HIP_MEMORY_SCOPE_AGENT) * (1.f / 2048.f);
        __syncthreads();
        for (int idx = tid; idx < 2048; idx += 256) {
            int bq = idx >> 7, n = idx & 127;
            float s = bo[n];
#pragma unroll 4
            for (int c = 0; c < 128; ++c) s += plbuf[bq * 128 + c] * Wo[c * 128 + n];
            midb[idx] = s;
        }
        __syncthreads();
        for (int idx = tid; idx < 8192; idx += 256) {
            int bq = idx >> 9, j = idx & 511;
            float s = bout[j];
#pragma unroll 4
            for (int i = 0; i < 128; ++i) s += midb[bq * 128 + i] * Wout[i * 512 + j];
            out[idx] = s;
        }
    }
}

// ---------------------------------------------------------------------------
extern "C" void kernel_launch(void* const* d_in, const int* in_sizes, int n_in,
                              void* d_out, int out_size, void* d_ws, size_t ws_size,
                              hipStream_t stream) {
    (void)in_sizes; (void)n_in; (void)out_size; (void)ws_size;
    const float* ohlc = (const float*)d_in[0];
    const float* Wp   = (const float*)d_in[1];  const float* bp   = (const float*)d_in[2];
    const float* Wc1  = (const float*)d_in[3];  const float* bc1  = (const float*)d_in[4];
    const float* Wc2  = (const float*)d_in[5];  const float* bc2  = (const float*)d_in[6];
    const float* Wv1  = (const float*)d_in[7];  const float* bv1  = (const float*)d_in[8];
    const float* Wv2  = (const float*)d_in[9];  const float* bv2  = (const float*)d_in[10];
    const float* Ws1  = (const float*)d_in[11]; const float* bs1  = (const float*)d_in[12];
    const float* Ws2  = (const float*)d_in[13]; const float* bs2  = (const float*)d_in[14];
    const float* Wqkv = (const float*)d_in[15]; const float* bqkv = (const float*)d_in[16];
    const float* Wo   = (const float*)d_in[17]; const float* bo   = (const float*)d_in[18];
    const float* Wout = (const float*)d_in[19]; const float* bout = (const float*)d_in[20];
    float* out = (float*)d_out;
    char* ws = (char*)d_ws;

    const size_t MB8 = 8388608;
    unsigned short* qg    = (unsigned short*)(ws);
    unsigned short* kg    = (unsigned short*)(ws + 1 * MB8);
    unsigned short* vt2   = (unsigned short*)(ws + 2 * MB8);
    float*          pooled = (float*)(ws + 3 * MB8);
    float*          qkmax  = (float*)(ws + 3 * MB8 + 8192);
    unsigned int*   done   = (unsigned int*)(ws + 3 * MB8 + 8192 + 512);
    unsigned short* wc1t  = (unsigned short*)(ws + 3 * MB8 + 8192 + 1024);
    unsigned short* wc2t  = wc1t + 8192;
    unsigned short* wv1t  = wc2t + 4096;
    unsigned short* wv2t  = wv1t + 4096;
    unsigned short* ws1t  = wv2t + 1024;
    unsigned short* ws2t  = ws1t + 4096;
    unsigned short* wqkvt = ws2t + 1024;

    prep_kernel<<<145, 256, 0, stream>>>(Wqkv, Wc1, Wc2, Wv1, Wv2, Ws1, Ws2,
                                         wqkvt, wc1t, wc2t, wv1t, wv2t, ws1t, ws2t,
                                         pooled, qkmax, done);
    trunk_kernel<<<512, 256, 0, stream>>>(ohlc, Wp, bp, wc1t, bc1, wc2t, bc2,
                                          wv1t, bv1, wv2t, bv2, ws1t, bs1, ws2t, bs2,
                                          wqkvt, bqkv, qg, kg, vt2, qkmax);
    attn_kernel<<<2048, 256, 0, stream>>>(qg, kg, vt2, qkmax, pooled, done,
                                          Wo, bo, Wout, bout, out);
}

// Round 11
// 143.556 us; speedup vs baseline: 2.9191x; 2.9191x over previous
//
#include <hip/hip_runtime.h>

// ---------------------------------------------------------------------------
// PriceGeometryEncoder on MI355X — round 11.
// prep -> fused_mlp (3-branch split, LDS-staged weights) -> QKV GEMM
// (coalesced q/k stores; V in kappa-permuted tiles) -> flash attention
// (r6 no-LDS no-barrier core, now 32 q/wave x 1024 blocks = 4 waves/SIMD)
// -> head.  out = (mean_t(o) @ Wo + bo) @ Wout + bout (mean commutes), so
// attention only emits column sums of O.
// ---------------------------------------------------------------------------

typedef __attribute__((ext_vector_type(4)))  float f32x4;
typedef __attribute__((ext_vector_type(4)))  short short4v;
typedef __attribute__((ext_vector_type(8)))  short short8v;

static __device__ __forceinline__ unsigned short f2b(float f) {
    unsigned int u = __builtin_bit_cast(unsigned int, f);
    u += 0x7fffu + ((u >> 16) & 1u);       // round-to-nearest-even
    return (unsigned short)(u >> 16);
}

static __device__ __forceinline__ unsigned int cvtpk_bf16(float a, float b) {
    unsigned int r;
    asm volatile("v_cvt_pk_bf16_f32 %0, %1, %2" : "=v"(r) : "v"(a), "v"(b));
    return r;
}

// ---------------------------------------------------------------------------
// K0: blocks 0..47: Wqkv [128][384] f32 -> [384][128] bf16 via 32x32 tiles.
//     blocks 48+ : small weight transposes + zero pooled/qkmax.
// ---------------------------------------------------------------------------
__global__ __launch_bounds__(256) void prep_kernel(
    const float* Wqkv, const float* Wc1, const float* Wc2, const float* Wv1,
    const float* Wv2, const float* Ws1, const float* Ws2,
    unsigned short* wqkvt, unsigned short* wc1t, unsigned short* wc2t,
    unsigned short* wv1t, unsigned short* wv2t, unsigned short* ws1t,
    unsigned short* ws2t, float* pooled, float* qkmax)
{
    int tid = threadIdx.x;
    if (blockIdx.x < 48) {
        __shared__ float tile[32][33];
        int bidn = blockIdx.x % 12, bidk = blockIdx.x / 12;
        int n0 = bidn * 32, k0 = bidk * 32;
        {
            int r = tid >> 3, cq = tid & 7;
            float4 v = *(const float4*)(Wqkv + (size_t)(k0 + r) * 384 + n0 + cq * 4);
            tile[r][cq*4+0] = v.x; tile[r][cq*4+1] = v.y;
            tile[r][cq*4+2] = v.z; tile[r][cq*4+3] = v.w;
        }
        __syncthreads();
        {
            int nr = tid >> 3, kq = tid & 7;
            union { unsigned short us[4]; short4v v; } pk;
#pragma unroll
            for (int j = 0; j < 4; ++j) pk.us[j] = f2b(tile[kq*4+j][nr]);
            *(short4v*)(wqkvt + (size_t)(n0 + nr) * 128 + k0 + kq * 4) = pk.v;
        }
        return;
    }
    int idx = (blockIdx.x - 48) * 256 + tid;
    if (idx < 8192)  { int n = idx >> 6, kk = idx & 63;  wc1t[idx] = f2b(Wc1[kk*128 + n]); return; }
    idx -= 8192;
    if (idx < 4096)  { int n = idx >> 7, kk = idx & 127; wc2t[idx] = f2b(Wc2[kk*32  + n]); return; }
    idx -= 4096;
    if (idx < 4096)  { int n = idx >> 6, kk = idx & 63;  wv1t[idx] = f2b(Wv1[kk*64  + n]); return; }
    idx -= 4096;
    if (idx < 1024)  { int n = idx >> 6, kk = idx & 63;  wv2t[idx] = f2b(Wv2[kk*16  + n]); return; }
    idx -= 1024;
    if (idx < 4096)  { int n = idx >> 6, kk = idx & 63;  ws1t[idx] = f2b(Ws1[kk*64  + n]); return; }
    idx -= 4096;
    if (idx < 1024)  { int n = idx >> 6, kk = idx & 63;  ws2t[idx] = f2b(Ws2[kk*16  + n]); return; }
    idx -= 1024;
    if (idx < 2048)  { pooled[idx] = 0.f; return; }
    idx -= 2048;
    if (idx < 128)   qkmax[idx] = 0.f;
}

// ---------------------------------------------------------------------------
// Stage weight matrix [N][K] bf16 (global) into LDS rows of K*2 bytes with
// 16B-slot XOR swizzle — coalesced b128 loads.
// ---------------------------------------------------------------------------
template<int N, int K>
static __device__ __forceinline__ void stage_w(
    const unsigned short* __restrict__ wt, char* Bs, int tid)
{
    constexpr int SL = K / 8;
#pragma unroll
    for (int c = tid; c < N * SL; c += 256) {
        int n = c / SL, s = c % SL;
        short8v v = *(const short8v*)(wt + n * K + s * 8);
        *(short8v*)(Bs + n * (K * 2) + ((s ^ (n & (SL - 1))) << 4)) = v;
    }
}

// ---------------------------------------------------------------------------
// Wave tile GEMM, A and B both from LDS (swizzled). 16 tokens/wave.
// ---------------------------------------------------------------------------
template<int N, int K, int A_ROWB, int D_ROWB, bool RELU, bool TO_LDS>
static __device__ __forceinline__ void tile_gemm_l(
    const char* As, const char* Bs, const float* __restrict__ bias, char* dst,
    unsigned short* __restrict__ gOut, int ocol, int m0, int w, int lane)
{
    constexpr int ASL = A_ROWB / 16, DSL = D_ROWB / 16, BSL = K / 8;
    constexpr int NT = N / 16, KS = K / 32;
    int l15 = lane & 15, hi4 = lane >> 4;
    f32x4 acc[NT];
#pragma unroll
    for (int nt = 0; nt < NT; ++nt)
#pragma unroll
        for (int r = 0; r < 4; ++r) acc[nt][r] = 0.f;

#pragma unroll
    for (int ks = 0; ks < KS; ++ks) {
        int slot = ks * 4 + hi4;
        int m = w * 16 + l15;
        short8v af = *(const short8v*)(As + m * A_ROWB + ((slot ^ (m & (ASL - 1))) << 4));
#pragma unroll
        for (int nt = 0; nt < NT; ++nt) {
            int n = nt * 16 + l15;
            short8v bf = *(const short8v*)(Bs + n * (K * 2) + ((slot ^ (n & (BSL - 1))) << 4));
            acc[nt] = __builtin_amdgcn_mfma_f32_16x16x32_bf16(af, bf, acc[nt], 0, 0, 0);
        }
    }
#pragma unroll
    for (int nt = 0; nt < NT; ++nt) {
        int n = nt * 16 + l15;
        float bv = bias[n];
#pragma unroll
        for (int r = 0; r < 4; ++r) {
            int m = w * 16 + hi4 * 4 + r;
            float v = acc[nt][r] + bv;
            if (RELU) v = fmaxf(v, 0.f);
            if (TO_LDS) {
                *(unsigned short*)(dst + m * D_ROWB + (((n >> 3) ^ (m & (DSL - 1))) << 4) + (n & 7) * 2) = f2b(v);
            } else {
                gOut[(size_t)(m0 + m) * 128 + ocol + n] = f2b(v);
            }
        }
    }
}

// ---------------------------------------------------------------------------
// K1: fused_mlp, 3-branch grid split, weights LDS-staged per block.
// ---------------------------------------------------------------------------
__global__ __launch_bounds__(256) void fused_mlp(
    const float* __restrict__ ohlc, const float* __restrict__ Wp, const float* __restrict__ bp,
    const unsigned short* __restrict__ wc1t, const float* __restrict__ bc1,
    const unsigned short* __restrict__ wc2t, const float* __restrict__ bc2,
    const unsigned short* __restrict__ wv1t, const float* __restrict__ bv1,
    const unsigned short* __restrict__ wv2t, const float* __restrict__ bv2,
    const unsigned short* __restrict__ ws1t, const float* __restrict__ bs1,
    const unsigned short* __restrict__ ws2t, const float* __restrict__ bs2,
    unsigned short* __restrict__ feats)
{
    __shared__ float wp[256];
    __shared__ float bpl[64];
    __shared__ char Et[64 * 128];
    __shared__ char Ht[64 * 256];
    __shared__ char Bw1[16384];
    __shared__ char Bw2[8192];

    int tid = threadIdx.x;
    int m0 = blockIdx.x * 64;
    int branch = blockIdx.y;
    wp[tid] = Wp[tid];
    if (tid < 64) bpl[tid] = bp[tid];

    if (branch == 0)      { stage_w<128, 64>(wc1t, Bw1, tid); stage_w<32, 128>(wc2t, Bw2, tid); }
    else if (branch == 1) { stage_w< 64, 64>(wv1t, Bw1, tid); stage_w<16,  64>(wv2t, Bw2, tid); }
    else                  { stage_w< 64, 64>(ws1t, Bw1, tid); stage_w<16,  64>(ws2t, Bw2, tid); }
    __syncthreads();

    {   // embed -> Et (wave-local rows) + feats[:,0:64] (branch 0 only)
        int tok = tid >> 2, jq = tid & 3;
        float4 ov = ((const float4*)ohlc)[m0 + tok];
#pragma unroll
        for (int c = 0; c < 2; ++c) {
            int sl = jq * 2 + c;
            union { unsigned short us[8]; short8v v; } pk;
#pragma unroll
            for (int jj = 0; jj < 8; ++jj) {
                int j = sl * 8 + jj;
                float e = bpl[j] + ov.x * wp[j] + ov.y * wp[64 + j]
                                 + ov.z * wp[128 + j] + ov.w * wp[192 + j];
                pk.us[jj] = f2b(e);
            }
            *(short8v*)(Et + tok * 128 + ((sl ^ (tok & 7)) << 4)) = pk.v;
            if (branch == 0)
                *(short8v*)(feats + (size_t)(m0 + tok) * 128 + sl * 8) = pk.v;
        }
    }
    // no barrier: each wave consumes exactly its own Et/Ht rows

    int lane = tid & 63, w = tid >> 6;
    if (branch == 0) {
        tile_gemm_l<128, 64, 128, 256, true, true >(Et, Bw1, bc1, Ht, feats, 0,  m0, w, lane);
        tile_gemm_l< 32, 128, 256, 256, false, false>(Ht, Bw2, bc2, Ht, feats, 64, m0, w, lane);
    } else if (branch == 1) {
        tile_gemm_l< 64, 64, 128, 128, true, true >(Et, Bw1, bv1, Ht, feats, 0,  m0, w, lane);
        tile_gemm_l< 16, 64, 128, 128, false, false>(Ht, Bw2, bv2, Ht, feats, 96, m0, w, lane);
    } else {
        tile_gemm_l< 64, 64, 128, 128, true, true >(Et, Bw1, bs1, Ht, feats, 0,   m0, w, lane);
        tile_gemm_l< 16, 64, 128, 128, false, false>(Ht, Bw2, bs2, Ht, feats, 112, m0, w, lane);
    }
}

// ---------------------------------------------------------------------------
// K2: QKV GEMM (known good, unchanged). sel=0/1 (q,k): LDS-bounce epilogue ->
// coalesced b128 stores into [bh][t][32]; amax via wave-reduce + atomicMax.
// sel=2 (v): kappa-permuted tiled stores vt2[bh][g32][dh][kappa].
// ---------------------------------------------------------------------------
__global__ __launch_bounds__(256) void qkv_gemm(
    const unsigned short* __restrict__ feats,
    const unsigned short* __restrict__ wqkvt, const float* __restrict__ bqkv,
    unsigned short* __restrict__ qg, unsigned short* __restrict__ kg,
    unsigned short* __restrict__ vt2, float* __restrict__ qkmax)
{
    constexpr int ROWB = 256, CPR = 16;
    __shared__ short8v smemv[4096];          // 64 KiB
    char* As = (char*)smemv;
    char* Bs = (char*)smemv + 32768;

    int tid = threadIdx.x;
    int m0 = blockIdx.x * 128;
    int sel = blockIdx.y;
    const unsigned short* BT = wqkvt + (size_t)sel * 128 * 128;

    for (int c = tid; c < 128 * CPR; c += 256) {
        int m = c / CPR, s = c % CPR;
        short8v v = *(const short8v*)(feats + (size_t)(m0 + m) * 128 + s * 8);
        *(short8v*)(As + m * ROWB + ((s ^ (m & 15)) * 16)) = v;
    }
    for (int c = tid; c < 128 * CPR; c += 256) {
        int n = c / CPR, s = c % CPR;
        short8v v = *(const short8v*)(BT + (size_t)n * 128 + s * 8);
        *(short8v*)(Bs + n * ROWB + ((s ^ (n & 15)) * 16)) = v;
    }
    __syncthreads();

    int lane = tid & 63, w = tid >> 6;
    int l15 = lane & 15, hi4 = lane >> 4;

    f32x4 acc[2][8];
#pragma unroll
    for (int mt = 0; mt < 2; ++mt)
#pragma unroll
        for (int nt = 0; nt < 8; ++nt)
#pragma unroll
            for (int r = 0; r < 4; ++r) acc[mt][nt][r] = 0.f;

#pragma unroll
    for (int ks = 0; ks < 4; ++ks) {
        int slot = ks * 4 + hi4;
        short8v af[2];
#pragma unroll
        for (int mt = 0; mt < 2; ++mt) {
            int m = w * 32 + mt * 16 + l15;
            af[mt] = *(const short8v*)(As + m * ROWB + ((slot ^ (m & 15)) * 16));
        }
#pragma unroll
        for (int nt = 0; nt < 8; ++nt) {
            int n = nt * 16 + l15;
            short8v bf = *(const short8v*)(Bs + n * ROWB + ((slot ^ (n & 15)) * 16));
            acc[0][nt] = __builtin_amdgcn_mfma_f32_16x16x32_bf16(af[0], bf, acc[0][nt], 0, 0, 0);
            acc[1][nt] = __builtin_amdgcn_mfma_f32_16x16x32_bf16(af[1], bf, acc[1][nt], 0, 0, 0);
        }
    }

    const float QSCALE = 1.4426950408889634f * 0.17677669529663687f; // log2e/sqrt(32)
    int b = m0 >> 11, tp0 = m0 & 2047;

    if (sel == 2) {
#pragma unroll
        for (int mt = 0; mt < 2; ++mt)
#pragma unroll
            for (int nt = 0; nt < 8; ++nt) {
                int n = nt * 16 + l15;
                float bv = bqkv[256 + n];
                int h = n >> 5, dh = n & 31;
                uint2 pk;
                pk.x = cvtpk_bf16(acc[mt][nt][0] + bv, acc[mt][nt][1] + bv);
                pk.y = cvtpk_bf16(acc[mt][nt][2] + bv, acc[mt][nt][3] + bv);
                int g32 = (tp0 >> 5) + w;
                size_t o = (size_t)(b * 4 + h) * 65536 + (size_t)g32 * 1024
                         + dh * 32 + hi4 * 8 + mt * 4;
                *(uint2*)(vt2 + o) = pk;
            }
    } else {
        float amax[4] = {0.f, 0.f, 0.f, 0.f};
        float scale = (sel == 0) ? QSCALE : 1.0f;
#pragma unroll
        for (int mt = 0; mt < 2; ++mt)
#pragma unroll
            for (int nt = 0; nt < 8; ++nt) {
                int n = nt * 16 + l15;
                float bv = bqkv[sel * 128 + n];
#pragma unroll
                for (int r = 0; r < 4; ++r) {
                    float v = (acc[mt][nt][r] + bv) * scale;
                    amax[nt >> 1] = fmaxf(amax[nt >> 1], fabsf(v));
                    int m = w * 32 + mt * 16 + hi4 * 4 + r;
                    *(unsigned short*)(As + m * 256 + (((n >> 3) ^ (m & 7)) << 4) + (n & 7) * 2) = f2b(v);
                }
            }
#pragma unroll
        for (int g = 0; g < 4; ++g) {
            float mv = amax[g];
            mv = fmaxf(mv, __shfl_xor(mv, 1));  mv = fmaxf(mv, __shfl_xor(mv, 2));
            mv = fmaxf(mv, __shfl_xor(mv, 4));  mv = fmaxf(mv, __shfl_xor(mv, 8));
            mv = fmaxf(mv, __shfl_xor(mv, 16)); mv = fmaxf(mv, __shfl_xor(mv, 32));
            if (lane == 0)
                atomicMax((int*)(qkmax + sel * 64 + b * 4 + g), __float_as_int(mv));
        }
        __syncthreads();
        unsigned short* og = (sel == 0) ? qg : kg;
#pragma unroll
        for (int it = 0; it < 8; ++it) {
            int ch = it * 256 + tid;
            int m = ch >> 4, c = ch & 15;
            short8v vv = *(const short8v*)(As + m * 256 + ((c ^ (m & 7)) << 4));
            int h = c >> 2, dq = c & 3;
            *(short8v*)(og + ((size_t)(b * 4 + h) * 2048 + tp0 + m) * 32 + dq * 8) = vv;
        }
    }
}

// ---------------------------------------------------------------------------
// K3: flash attention — r6 no-LDS no-barrier core, 32 q/wave, grid 1024
// (4 blocks/CU = 4 waves/SIMD; r6 had 2). All loads coalesced 1KB; K/V
// register-double-buffered one 32-key group ahead. Static-max softmax
// (NEGM4 C-init); lsum via ones-MFMA. bh = bid&63 keeps a (b,h) on one XCD.
// ---------------------------------------------------------------------------
__global__ __launch_bounds__(256) void attn_kernel(
    const unsigned short* __restrict__ qg, const unsigned short* __restrict__ kg,
    const unsigned short* __restrict__ vt2, const float* __restrict__ qkmax,
    float* __restrict__ pooled)
{
    int tid = threadIdx.x, bid = blockIdx.x;
    int bh = bid & 63, qc = bid >> 6;          // qc 0..15
    int b = bh >> 2;
    int lane = tid & 63, w = tid >> 6;
    int l15 = lane & 15, h = (lane >> 4) & 3;
    int q0 = qc * 128 + w * 32;

    // Q B-frags: lane(l15,h) holds Q[q0+j*16+l15][kd 8h..8h+7] — coalesced
    const char* qp = (const char*)qg + ((size_t)bh * 2048 + q0) * 64 + l15 * 64 + h * 16;
    short8v Qf[2];
    Qf[0] = *(const short8v*)(qp);
    Qf[1] = *(const short8v*)(qp + 1024);

    float negM0 = -(32.0f * qkmax[bh] * qkmax[64 + bh]);
    f32x4 NEGM4 = {negM0, negM0, negM0, negM0};

    f32x4 accO[2][2], lacc[2];
#pragma unroll
    for (int j = 0; j < 2; ++j)
#pragma unroll
        for (int r = 0; r < 4; ++r) { accO[j][0][r] = 0.f; accO[j][1][r] = 0.f; lacc[j][r] = 0.f; }

    short8v ONES;
    {
        union { unsigned short us[8]; short8v v; } u;
#pragma unroll
        for (int j = 0; j < 8; ++j) u.us[j] = 0x3F80;      // bf16 1.0
        ONES = u.v;
    }

    // K: A-frag of 16-key tile = contiguous 1KB; V: kappa tiles, same shape.
    const char* kc = (const char*)kg  + (size_t)bh * 131072 + l15 * 64 + h * 16;
    const char* vc = (const char*)vt2 + (size_t)bh * 131072 + l15 * 64 + h * 16;

    auto compute = [&](short8v Ka, short8v Kb, short8v Va, short8v Vb) {
        union { unsigned int u[4]; short8v v; } pk[2];
#pragma unroll
        for (int tau = 0; tau < 2; ++tau) {
            short8v Kf = tau ? Kb : Ka;
#pragma unroll
            for (int j = 0; j < 2; ++j) {
                f32x4 s = __builtin_amdgcn_mfma_f32_16x16x32_bf16(Kf, Qf[j], NEGM4, 0, 0, 0);
                float p0 = __builtin_amdgcn_exp2f(s[0]);
                float p1 = __builtin_amdgcn_exp2f(s[1]);
                float p2 = __builtin_amdgcn_exp2f(s[2]);
                float p3 = __builtin_amdgcn_exp2f(s[3]);
                pk[j].u[tau * 2 + 0] = cvtpk_bf16(p0, p1);
                pk[j].u[tau * 2 + 1] = cvtpk_bf16(p2, p3);
            }
        }
#pragma unroll
        for (int j = 0; j < 2; ++j) {
            lacc[j]    = __builtin_amdgcn_mfma_f32_16x16x32_bf16(ONES, pk[j].v, lacc[j], 0, 0, 0);
            accO[j][0] = __builtin_amdgcn_mfma_f32_16x16x32_bf16(Va,   pk[j].v, accO[j][0], 0, 0, 0);
            accO[j][1] = __builtin_amdgcn_mfma_f32_16x16x32_bf16(Vb,   pk[j].v, accO[j][1], 0, 0, 0);
        }
    };

    short8v KaE, KbE, VaE, VbE, KaO, KbO, VaO, VbO;
    KaE = *(const short8v*)(kc);
    KbE = *(const short8v*)(kc + 1024);
    VaE = *(const short8v*)(vc);
    VbE = *(const short8v*)(vc + 1024);

#pragma unroll 1
    for (int g = 0; g < 64; g += 2) {
        {
            const char* kn = kc + (size_t)(g + 1) * 2048;
            const char* vn = vc + (size_t)(g + 1) * 2048;
            KaO = *(const short8v*)(kn);
            KbO = *(const short8v*)(kn + 1024);
            VaO = *(const short8v*)(vn);
            VbO = *(const short8v*)(vn + 1024);
        }
        compute(KaE, KbE, VaE, VbE);
        if (g + 2 < 64) {
            const char* kn = kc + (size_t)(g + 2) * 2048;
            const char* vn = vc + (size_t)(g + 2) * 2048;
            KaE = *(const short8v*)(kn);
            KbE = *(const short8v*)(kn + 1024);
            VaE = *(const short8v*)(vn);
            VbE = *(const short8v*)(vn + 1024);
        }
        compute(KaO, KbO, VaO, VbO);
    }

    // normalize per q (lane-local lsum), reduce over the 16 q's per l15-group,
    // atomically add column sums to pooled.
    float o8[2][4];
#pragma unroll
    for (int d = 0; d < 2; ++d)
#pragma unroll
        for (int r = 0; r < 4; ++r) o8[d][r] = 0.f;
#pragma unroll
    for (int j = 0; j < 2; ++j) {
        float inv = 1.0f / (lacc[j][0] + 1e-30f);
#pragma unroll
        for (int d = 0; d < 2; ++d)
#pragma unroll
            for (int r = 0; r < 4; ++r) o8[d][r] += accO[j][d][r] * inv;
    }
#pragma unroll
    for (int d = 0; d < 2; ++d)
#pragma unroll
        for (int r = 0; r < 4; ++r) {
            float v = o8[d][r];
            v += __shfl_xor(v, 1); v += __shfl_xor(v, 2);
            v += __shfl_xor(v, 4); v += __shfl_xor(v, 8);
            if (l15 == 0) {
                int dh = d * 16 + h * 4 + r;
                atomicAdd(pooled + b * 128 + (bh & 3) * 32 + dh, v);
            }
        }
}

// ---------------------------------------------------------------------------
// K4: out[b] = (pooled[b]/2048 @ Wo + bo) @ Wout + bout   (f32, tiny)
// ---------------------------------------------------------------------------
__global__ __launch_bounds__(256) void head_kernel(
    const float* __restrict__ pooled, const float* __restrict__ Wo,
    const float* __restrict__ bo, const float* __restrict__ Wout,
    const float* __restrict__ bout, float* __restrict__ out)
{
    int bq = blockIdx.x, tid = threadIdx.x;
    __shared__ float pl[128], mid[128];
    if (tid < 128) pl[tid] = pooled[bq * 128 + tid] * (1.f / 2048.f);
    __syncthreads();
    if (tid < 128) {
        float s = bo[tid];
#pragma unroll 4
        for (int c = 0; c < 128; ++c) s += pl[c] * Wo[c * 128 + tid];
        mid[tid] = s;
    }
    __syncthreads();
    for (int j = tid; j < 512; j += 256) {
        float s = bout[j];
#pragma unroll 4
        for (int i = 0; i < 128; ++i) s += mid[i] * Wout[i * 512 + j];
        out[bq * 512 + j] = s;
    }
}

// ---------------------------------------------------------------------------
extern "C" void kernel_launch(void* const* d_in, const int* in_sizes, int n_in,
                              void* d_out, int out_size, void* d_ws, size_t ws_size,
                              hipStream_t stream) {
    (void)in_sizes; (void)n_in; (void)out_size; (void)ws_size;
    const float* ohlc = (const float*)d_in[0];
    const float* Wp   = (const float*)d_in[1];  const float* bp   = (const float*)d_in[2];
    const float* Wc1  = (const float*)d_in[3];  const float* bc1  = (const float*)d_in[4];
    const float* Wc2  = (const float*)d_in[5];  const float* bc2  = (const float*)d_in[6];
    const float* Wv1  = (const float*)d_in[7];  const float* bv1  = (const float*)d_in[8];
    const float* Wv2  = (const float*)d_in[9];  const float* bv2  = (const float*)d_in[10];
    const float* Ws1  = (const float*)d_in[11]; const float* bs1  = (const float*)d_in[12];
    const float* Ws2  = (const float*)d_in[13]; const float* bs2  = (const float*)d_in[14];
    const float* Wqkv = (const float*)d_in[15]; const float* bqkv = (const float*)d_in[16];
    const float* Wo   = (const float*)d_in[17]; const float* bo   = (const float*)d_in[18];
    const float* Wout = (const float*)d_in[19]; const float* bout = (const float*)d_in[20];
    float* out = (float*)d_out;
    char* ws = (char*)d_ws;

    const size_t MB8 = 8388608;
    unsigned short* feats = (unsigned short*)(ws);
    unsigned short* qg    = (unsigned short*)(ws + 1 * MB8);
    unsigned short* kg    = (unsigned short*)(ws + 2 * MB8);
    unsigned short* vt2   = (unsigned short*)(ws + 3 * MB8);
    float*          pooled = (float*)(ws + 4 * MB8);
    float*          qkmax  = (float*)(ws + 4 * MB8 + 8192);
    unsigned short* wc1t  = (unsigned short*)(ws + 4 * MB8 + 8192 + 512);
    unsigned short* wc2t  = wc1t + 8192;
    unsigned short* wv1t  = wc2t + 4096;
    unsigned short* wv2t  = wv1t + 4096;
    unsigned short* ws1t  = wv2t + 1024;
    unsigned short* ws2t  = ws1t + 4096;
    unsigned short* wqkvt = ws2t + 1024;

    prep_kernel<<<145, 256, 0, stream>>>(Wqkv, Wc1, Wc2, Wv1, Wv2, Ws1, Ws2,
                                         wqkvt, wc1t, wc2t, wv1t, wv2t, ws1t, ws2t,
                                         pooled, qkmax);
    fused_mlp<<<dim3(512, 3), 256, 0, stream>>>(ohlc, Wp, bp, wc1t, bc1, wc2t, bc2,
                                                wv1t, bv1, wv2t, bv2, ws1t, bs1, ws2t, bs2, feats);
    qkv_gemm<<<dim3(256, 3), 256, 0, stream>>>(feats, wqkvt, bqkv, qg, kg, vt2, qkmax);
    attn_kernel<<<1024, 256, 0, stream>>>(qg, kg, vt2, qkmax, pooled);
    head_kernel<<<16, 256, 0, stream>>>(pooled, Wo, bo, Wout, bout, out);
}

// Round 12
// 124.783 us; speedup vs baseline: 3.3583x; 1.1504x over previous
//
#include <hip/hip_runtime.h>

// ---------------------------------------------------------------------------
// PriceGeometryEncoder on MI355X — round 12.
// Best-known assembly: r11 residue (prep + 3-branch fused_mlp with LDS-staged
// weights + qkv) + r6 attention core (64 q/wave, grid 512, no LDS/barriers,
// all loads coalesced 1KB, static-max softmax, ones-MFMA lsum).
// out = (mean_t(o) @ Wo + bo) @ Wout + bout (mean commutes), so attention
// only emits column sums of O.
// ---------------------------------------------------------------------------

typedef __attribute__((ext_vector_type(4)))  float f32x4;
typedef __attribute__((ext_vector_type(4)))  short short4v;
typedef __attribute__((ext_vector_type(8)))  short short8v;

static __device__ __forceinline__ unsigned short f2b(float f) {
    unsigned int u = __builtin_bit_cast(unsigned int, f);
    u += 0x7fffu + ((u >> 16) & 1u);       // round-to-nearest-even
    return (unsigned short)(u >> 16);
}

static __device__ __forceinline__ unsigned int cvtpk_bf16(float a, float b) {
    unsigned int r;
    asm volatile("v_cvt_pk_bf16_f32 %0, %1, %2" : "=v"(r) : "v"(a), "v"(b));
    return r;
}

// ---------------------------------------------------------------------------
// K0: blocks 0..47: Wqkv [128][384] f32 -> [384][128] bf16 via 32x32 tiles.
//     blocks 48+ : small weight transposes + zero pooled/qkmax.
// ---------------------------------------------------------------------------
__global__ __launch_bounds__(256) void prep_kernel(
    const float* Wqkv, const float* Wc1, const float* Wc2, const float* Wv1,
    const float* Wv2, const float* Ws1, const float* Ws2,
    unsigned short* wqkvt, unsigned short* wc1t, unsigned short* wc2t,
    unsigned short* wv1t, unsigned short* wv2t, unsigned short* ws1t,
    unsigned short* ws2t, float* pooled, float* qkmax)
{
    int tid = threadIdx.x;
    if (blockIdx.x < 48) {
        __shared__ float tile[32][33];
        int bidn = blockIdx.x % 12, bidk = blockIdx.x / 12;
        int n0 = bidn * 32, k0 = bidk * 32;
        {
            int r = tid >> 3, cq = tid & 7;
            float4 v = *(const float4*)(Wqkv + (size_t)(k0 + r) * 384 + n0 + cq * 4);
            tile[r][cq*4+0] = v.x; tile[r][cq*4+1] = v.y;
            tile[r][cq*4+2] = v.z; tile[r][cq*4+3] = v.w;
        }
        __syncthreads();
        {
            int nr = tid >> 3, kq = tid & 7;
            union { unsigned short us[4]; short4v v; } pk;
#pragma unroll
            for (int j = 0; j < 4; ++j) pk.us[j] = f2b(tile[kq*4+j][nr]);
            *(short4v*)(wqkvt + (size_t)(n0 + nr) * 128 + k0 + kq * 4) = pk.v;
        }
        return;
    }
    int idx = (blockIdx.x - 48) * 256 + tid;
    if (idx < 8192)  { int n = idx >> 6, kk = idx & 63;  wc1t[idx] = f2b(Wc1[kk*128 + n]); return; }
    idx -= 8192;
    if (idx < 4096)  { int n = idx >> 7, kk = idx & 127; wc2t[idx] = f2b(Wc2[kk*32  + n]); return; }
    idx -= 4096;
    if (idx < 4096)  { int n = idx >> 6, kk = idx & 63;  wv1t[idx] = f2b(Wv1[kk*64  + n]); return; }
    idx -= 4096;
    if (idx < 1024)  { int n = idx >> 6, kk = idx & 63;  wv2t[idx] = f2b(Wv2[kk*16  + n]); return; }
    idx -= 1024;
    if (idx < 4096)  { int n = idx >> 6, kk = idx & 63;  ws1t[idx] = f2b(Ws1[kk*64  + n]); return; }
    idx -= 4096;
    if (idx < 1024)  { int n = idx >> 6, kk = idx & 63;  ws2t[idx] = f2b(Ws2[kk*16  + n]); return; }
    idx -= 1024;
    if (idx < 2048)  { pooled[idx] = 0.f; return; }
    idx -= 2048;
    if (idx < 128)   qkmax[idx] = 0.f;
}

// ---------------------------------------------------------------------------
// Stage weight matrix [N][K] bf16 (global) into LDS rows of K*2 bytes with
// 16B-slot XOR swizzle — coalesced b128 loads.
// ---------------------------------------------------------------------------
template<int N, int K>
static __device__ __forceinline__ void stage_w(
    const unsigned short* __restrict__ wt, char* Bs, int tid)
{
    constexpr int SL = K / 8;
#pragma unroll
    for (int c = tid; c < N * SL; c += 256) {
        int n = c / SL, s = c % SL;
        short8v v = *(const short8v*)(wt + n * K + s * 8);
        *(short8v*)(Bs + n * (K * 2) + ((s ^ (n & (SL - 1))) << 4)) = v;
    }
}

// ---------------------------------------------------------------------------
// Wave tile GEMM, A and B both from LDS (swizzled). 16 tokens/wave.
// ---------------------------------------------------------------------------
template<int N, int K, int A_ROWB, int D_ROWB, bool RELU, bool TO_LDS>
static __device__ __forceinline__ void tile_gemm_l(
    const char* As, const char* Bs, const float* __restrict__ bias, char* dst,
    unsigned short* __restrict__ gOut, int ocol, int m0, int w, int lane)
{
    constexpr int ASL = A_ROWB / 16, DSL = D_ROWB / 16, BSL = K / 8;
    constexpr int NT = N / 16, KS = K / 32;
    int l15 = lane & 15, hi4 = lane >> 4;
    f32x4 acc[NT];
#pragma unroll
    for (int nt = 0; nt < NT; ++nt)
#pragma unroll
        for (int r = 0; r < 4; ++r) acc[nt][r] = 0.f;

#pragma unroll
    for (int ks = 0; ks < KS; ++ks) {
        int slot = ks * 4 + hi4;
        int m = w * 16 + l15;
        short8v af = *(const short8v*)(As + m * A_ROWB + ((slot ^ (m & (ASL - 1))) << 4));
#pragma unroll
        for (int nt = 0; nt < NT; ++nt) {
            int n = nt * 16 + l15;
            short8v bf = *(const short8v*)(Bs + n * (K * 2) + ((slot ^ (n & (BSL - 1))) << 4));
            acc[nt] = __builtin_amdgcn_mfma_f32_16x16x32_bf16(af, bf, acc[nt], 0, 0, 0);
        }
    }
#pragma unroll
    for (int nt = 0; nt < NT; ++nt) {
        int n = nt * 16 + l15;
        float bv = bias[n];
#pragma unroll
        for (int r = 0; r < 4; ++r) {
            int m = w * 16 + hi4 * 4 + r;
            float v = acc[nt][r] + bv;
            if (RELU) v = fmaxf(v, 0.f);
            if (TO_LDS) {
                *(unsigned short*)(dst + m * D_ROWB + (((n >> 3) ^ (m & (DSL - 1))) << 4) + (n & 7) * 2) = f2b(v);
            } else {
                gOut[(size_t)(m0 + m) * 128 + ocol + n] = f2b(v);
            }
        }
    }
}

// ---------------------------------------------------------------------------
// K1: fused_mlp, 3-branch grid split, weights LDS-staged per block.
// ---------------------------------------------------------------------------
__global__ __launch_bounds__(256) void fused_mlp(
    const float* __restrict__ ohlc, const float* __restrict__ Wp, const float* __restrict__ bp,
    const unsigned short* __restrict__ wc1t, const float* __restrict__ bc1,
    const unsigned short* __restrict__ wc2t, const float* __restrict__ bc2,
    const unsigned short* __restrict__ wv1t, const float* __restrict__ bv1,
    const unsigned short* __restrict__ wv2t, const float* __restrict__ bv2,
    const unsigned short* __restrict__ ws1t, const float* __restrict__ bs1,
    const unsigned short* __restrict__ ws2t, const float* __restrict__ bs2,
    unsigned short* __restrict__ feats)
{
    __shared__ float wp[256];
    __shared__ float bpl[64];
    __shared__ char Et[64 * 128];
    __shared__ char Ht[64 * 256];
    __shared__ char Bw1[16384];
    __shared__ char Bw2[8192];

    int tid = threadIdx.x;
    int m0 = blockIdx.x * 64;
    int branch = blockIdx.y;
    wp[tid] = Wp[tid];
    if (tid < 64) bpl[tid] = bp[tid];

    if (branch == 0)      { stage_w<128, 64>(wc1t, Bw1, tid); stage_w<32, 128>(wc2t, Bw2, tid); }
    else if (branch == 1) { stage_w< 64, 64>(wv1t, Bw1, tid); stage_w<16,  64>(wv2t, Bw2, tid); }
    else                  { stage_w< 64, 64>(ws1t, Bw1, tid); stage_w<16,  64>(ws2t, Bw2, tid); }
    __syncthreads();

    {   // embed -> Et (wave-local rows) + feats[:,0:64] (branch 0 only)
        int tok = tid >> 2, jq = tid & 3;
        float4 ov = ((const float4*)ohlc)[m0 + tok];
#pragma unroll
        for (int c = 0; c < 2; ++c) {
            int sl = jq * 2 + c;
            union { unsigned short us[8]; short8v v; } pk;
#pragma unroll
            for (int jj = 0; jj < 8; ++jj) {
                int j = sl * 8 + jj;
                float e = bpl[j] + ov.x * wp[j] + ov.y * wp[64 + j]
                                 + ov.z * wp[128 + j] + ov.w * wp[192 + j];
                pk.us[jj] = f2b(e);
            }
            *(short8v*)(Et + tok * 128 + ((sl ^ (tok & 7)) << 4)) = pk.v;
            if (branch == 0)
                *(short8v*)(feats + (size_t)(m0 + tok) * 128 + sl * 8) = pk.v;
        }
    }
    // no barrier: each wave consumes exactly its own Et/Ht rows

    int lane = tid & 63, w = tid >> 6;
    if (branch == 0) {
        tile_gemm_l<128, 64, 128, 256, true, true >(Et, Bw1, bc1, Ht, feats, 0,  m0, w, lane);
        tile_gemm_l< 32, 128, 256, 256, false, false>(Ht, Bw2, bc2, Ht, feats, 64, m0, w, lane);
    } else if (branch == 1) {
        tile_gemm_l< 64, 64, 128, 128, true, true >(Et, Bw1, bv1, Ht, feats, 0,  m0, w, lane);
        tile_gemm_l< 16, 64, 128, 128, false, false>(Ht, Bw2, bv2, Ht, feats, 96, m0, w, lane);
    } else {
        tile_gemm_l< 64, 64, 128, 128, true, true >(Et, Bw1, bs1, Ht, feats, 0,   m0, w, lane);
        tile_gemm_l< 16, 64, 128, 128, false, false>(Ht, Bw2, bs2, Ht, feats, 112, m0, w, lane);
    }
}

// ---------------------------------------------------------------------------
// K2: QKV GEMM (known good, unchanged). sel=0/1 (q,k): LDS-bounce epilogue ->
// coalesced b128 stores into [bh][t][32]; amax via wave-reduce + atomicMax.
// sel=2 (v): kappa-permuted tiled stores vt2[bh][g32][dh][kappa].
// ---------------------------------------------------------------------------
__global__ __launch_bounds__(256) void qkv_gemm(
    const unsigned short* __restrict__ feats,
    const unsigned short* __restrict__ wqkvt, const float* __restrict__ bqkv,
    unsigned short* __restrict__ qg, unsigned short* __restrict__ kg,
    unsigned short* __restrict__ vt2, float* __restrict__ qkmax)
{
    constexpr int ROWB = 256, CPR = 16;
    __shared__ short8v smemv[4096];          // 64 KiB
    char* As = (char*)smemv;
    char* Bs = (char*)smemv + 32768;

    int tid = threadIdx.x;
    int m0 = blockIdx.x * 128;
    int sel = blockIdx.y;
    const unsigned short* BT = wqkvt + (size_t)sel * 128 * 128;

    for (int c = tid; c < 128 * CPR; c += 256) {
        int m = c / CPR, s = c % CPR;
        short8v v = *(const short8v*)(feats + (size_t)(m0 + m) * 128 + s * 8);
        *(short8v*)(As + m * ROWB + ((s ^ (m & 15)) * 16)) = v;
    }
    for (int c = tid; c < 128 * CPR; c += 256) {
        int n = c / CPR, s = c % CPR;
        short8v v = *(const short8v*)(BT + (size_t)n * 128 + s * 8);
        *(short8v*)(Bs + n * ROWB + ((s ^ (n & 15)) * 16)) = v;
    }
    __syncthreads();

    int lane = tid & 63, w = tid >> 6;
    int l15 = lane & 15, hi4 = lane >> 4;

    f32x4 acc[2][8];
#pragma unroll
    for (int mt = 0; mt < 2; ++mt)
#pragma unroll
        for (int nt = 0; nt < 8; ++nt)
#pragma unroll
            for (int r = 0; r < 4; ++r) acc[mt][nt][r] = 0.f;

#pragma unroll
    for (int ks = 0; ks < 4; ++ks) {
        int slot = ks * 4 + hi4;
        short8v af[2];
#pragma unroll
        for (int mt = 0; mt < 2; ++mt) {
            int m = w * 32 + mt * 16 + l15;
            af[mt] = *(const short8v*)(As + m * ROWB + ((slot ^ (m & 15)) * 16));
        }
#pragma unroll
        for (int nt = 0; nt < 8; ++nt) {
            int n = nt * 16 + l15;
            short8v bf = *(const short8v*)(Bs + n * ROWB + ((slot ^ (n & 15)) * 16));
            acc[0][nt] = __builtin_amdgcn_mfma_f32_16x16x32_bf16(af[0], bf, acc[0][nt], 0, 0, 0);
            acc[1][nt] = __builtin_amdgcn_mfma_f32_16x16x32_bf16(af[1], bf, acc[1][nt], 0, 0, 0);
        }
    }

    const float QSCALE = 1.4426950408889634f * 0.17677669529663687f; // log2e/sqrt(32)
    int b = m0 >> 11, tp0 = m0 & 2047;

    if (sel == 2) {
#pragma unroll
        for (int mt = 0; mt < 2; ++mt)
#pragma unroll
            for (int nt = 0; nt < 8; ++nt) {
                int n = nt * 16 + l15;
                float bv = bqkv[256 + n];
                int h = n >> 5, dh = n & 31;
                uint2 pk;
                pk.x = cvtpk_bf16(acc[mt][nt][0] + bv, acc[mt][nt][1] + bv);
                pk.y = cvtpk_bf16(acc[mt][nt][2] + bv, acc[mt][nt][3] + bv);
                int g32 = (tp0 >> 5) + w;
                size_t o = (size_t)(b * 4 + h) * 65536 + (size_t)g32 * 1024
                         + dh * 32 + hi4 * 8 + mt * 4;
                *(uint2*)(vt2 + o) = pk;
            }
    } else {
        float amax[4] = {0.f, 0.f, 0.f, 0.f};
        float scale = (sel == 0) ? QSCALE : 1.0f;
#pragma unroll
        for (int mt = 0; mt < 2; ++mt)
#pragma unroll
            for (int nt = 0; nt < 8; ++nt) {
                int n = nt * 16 + l15;
                float bv = bqkv[sel * 128 + n];
#pragma unroll
                for (int r = 0; r < 4; ++r) {
                    float v = (acc[mt][nt][r] + bv) * scale;
                    amax[nt >> 1] = fmaxf(amax[nt >> 1], fabsf(v));
                    int m = w * 32 + mt * 16 + hi4 * 4 + r;
                    *(unsigned short*)(As + m * 256 + (((n >> 3) ^ (m & 7)) << 4) + (n & 7) * 2) = f2b(v);
                }
            }
#pragma unroll
        for (int g = 0; g < 4; ++g) {
            float mv = amax[g];
            mv = fmaxf(mv, __shfl_xor(mv, 1));  mv = fmaxf(mv, __shfl_xor(mv, 2));
            mv = fmaxf(mv, __shfl_xor(mv, 4));  mv = fmaxf(mv, __shfl_xor(mv, 8));
            mv = fmaxf(mv, __shfl_xor(mv, 16)); mv = fmaxf(mv, __shfl_xor(mv, 32));
            if (lane == 0)
                atomicMax((int*)(qkmax + sel * 64 + b * 4 + g), __float_as_int(mv));
        }
        __syncthreads();
        unsigned short* og = (sel == 0) ? qg : kg;
#pragma unroll
        for (int it = 0; it < 8; ++it) {
            int ch = it * 256 + tid;
            int m = ch >> 4, c = ch & 15;
            short8v vv = *(const short8v*)(As + m * 256 + ((c ^ (m & 7)) << 4));
            int h = c >> 2, dq = c & 3;
            *(short8v*)(og + ((size_t)(b * 4 + h) * 2048 + tp0 + m) * 32 + dq * 8) = vv;
        }
    }
}

// ---------------------------------------------------------------------------
// K3: flash attention — r6 core verbatim: 16x16x32 MFMA, all loads coalesced
// 1KB, no LDS, no barriers, 64 q-rows/wave (4 Q-frags), 64 32-key groups,
// K/V register-double-buffered one group ahead. Static-max softmax (NEGM4
// C-init); lsum via ones-MFMA. bh = bid&63 keeps a (b,h) on one XCD's L2.
// ---------------------------------------------------------------------------
__global__ __launch_bounds__(256, 2) void attn_kernel(
    const unsigned short* __restrict__ qg, const unsigned short* __restrict__ kg,
    const unsigned short* __restrict__ vt2, const float* __restrict__ qkmax,
    float* __restrict__ pooled)
{
    int tid = threadIdx.x, bid = blockIdx.x;
    int bh = bid & 63, qc = bid >> 6;
    int b = bh >> 2;
    int lane = tid & 63, w = tid >> 6;
    int l15 = lane & 15, h = (lane >> 4) & 3;
    int q0 = qc * 256 + w * 64;

    // Q B-frags: lane(l15,h) holds Q[q0+j*16+l15][kd 8h..8h+7] — coalesced
    const char* qp = (const char*)qg + ((size_t)bh * 2048 + q0) * 64 + l15 * 64 + h * 16;
    short8v Qf[4];
#pragma unroll
    for (int j = 0; j < 4; ++j) Qf[j] = *(const short8v*)(qp + j * 1024);

    float negM0 = -(32.0f * qkmax[bh] * qkmax[64 + bh]);
    f32x4 NEGM4 = {negM0, negM0, negM0, negM0};

    f32x4 accO[4][2], lacc[4];
#pragma unroll
    for (int j = 0; j < 4; ++j) {
#pragma unroll
        for (int r = 0; r < 4; ++r) { accO[j][0][r] = 0.f; accO[j][1][r] = 0.f; lacc[j][r] = 0.f; }
    }

    short8v ONES;
    {
        union { unsigned short us[8]; short8v v; } u;
#pragma unroll
        for (int j = 0; j < 8; ++j) u.us[j] = 0x3F80;      // bf16 1.0
        ONES = u.v;
    }

    // K: A-frag of 16-key tile = contiguous 1KB; V: kappa tiles, same shape.
    const char* kc = (const char*)kg  + (size_t)bh * 131072 + l15 * 64 + h * 16;
    const char* vc = (const char*)vt2 + (size_t)bh * 131072 + l15 * 64 + h * 16;

    auto compute = [&](short8v Ka, short8v Kb, short8v Va, short8v Vb) {
        union { unsigned int u[4]; short8v v; } pk[4];
#pragma unroll
        for (int tau = 0; tau < 2; ++tau) {
            short8v Kf = tau ? Kb : Ka;
#pragma unroll
            for (int j = 0; j < 4; ++j) {
                f32x4 s = __builtin_amdgcn_mfma_f32_16x16x32_bf16(Kf, Qf[j], NEGM4, 0, 0, 0);
                float p0 = __builtin_amdgcn_exp2f(s[0]);
                float p1 = __builtin_amdgcn_exp2f(s[1]);
                float p2 = __builtin_amdgcn_exp2f(s[2]);
                float p3 = __builtin_amdgcn_exp2f(s[3]);
                pk[j].u[tau * 2 + 0] = cvtpk_bf16(p0, p1);
                pk[j].u[tau * 2 + 1] = cvtpk_bf16(p2, p3);
            }
        }
#pragma unroll
        for (int j = 0; j < 4; ++j) {
            lacc[j]    = __builtin_amdgcn_mfma_f32_16x16x32_bf16(ONES, pk[j].v, lacc[j], 0, 0, 0);
            accO[j][0] = __builtin_amdgcn_mfma_f32_16x16x32_bf16(Va,   pk[j].v, accO[j][0], 0, 0, 0);
            accO[j][1] = __builtin_amdgcn_mfma_f32_16x16x32_bf16(Vb,   pk[j].v, accO[j][1], 0, 0, 0);
        }
    };

    short8v KaE, KbE, VaE, VbE, KaO, KbO, VaO, VbO;
    KaE = *(const short8v*)(kc);
    KbE = *(const short8v*)(kc + 1024);
    VaE = *(const short8v*)(vc);
    VbE = *(const short8v*)(vc + 1024);

#pragma unroll 1
    for (int g = 0; g < 64; g += 2) {
        {
            const char* kn = kc + (size_t)(g + 1) * 2048;
            const char* vn = vc + (size_t)(g + 1) * 2048;
            KaO = *(const short8v*)(kn);
            KbO = *(const short8v*)(kn + 1024);
            VaO = *(const short8v*)(vn);
            VbO = *(const short8v*)(vn + 1024);
        }
        compute(KaE, KbE, VaE, VbE);
        if (g + 2 < 64) {
            const char* kn = kc + (size_t)(g + 2) * 2048;
            const char* vn = vc + (size_t)(g + 2) * 2048;
            KaE = *(const short8v*)(kn);
            KbE = *(const short8v*)(kn + 1024);
            VaE = *(const short8v*)(vn);
            VbE = *(const short8v*)(vn + 1024);
        }
        compute(KaO, KbO, VaO, VbO);
    }

    // normalize per q (lane-local lsum!), sum over 4 q-frags, reduce over the
    // 16 q's in the lane's l15-group, atomically add column sums to pooled.
    float o8[2][4];
#pragma unroll
    for (int d = 0; d < 2; ++d)
#pragma unroll
        for (int r = 0; r < 4; ++r) o8[d][r] = 0.f;
#pragma unroll
    for (int j = 0; j < 4; ++j) {
        float inv = 1.0f / (lacc[j][0] + 1e-30f);
#pragma unroll
        for (int d = 0; d < 2; ++d)
#pragma unroll
            for (int r = 0; r < 4; ++r) o8[d][r] += accO[j][d][r] * inv;
    }
#pragma unroll
    for (int d = 0; d < 2; ++d)
#pragma unroll
        for (int r = 0; r < 4; ++r) {
            float v = o8[d][r];
            v += __shfl_xor(v, 1); v += __shfl_xor(v, 2);
            v += __shfl_xor(v, 4); v += __shfl_xor(v, 8);
            if (l15 == 0) {
                int dh = d * 16 + h * 4 + r;
                atomicAdd(pooled + b * 128 + (bh & 3) * 32 + dh, v);
            }
        }
}

// ---------------------------------------------------------------------------
// K4: out[b] = (pooled[b]/2048 @ Wo + bo) @ Wout + bout   (f32, tiny)
// ---------------------------------------------------------------------------
__global__ __launch_bounds__(256) void head_kernel(
    const float* __restrict__ pooled, const float* __restrict__ Wo,
    const float* __restrict__ bo, const float* __restrict__ Wout,
    const float* __restrict__ bout, float* __restrict__ out)
{
    int bq = blockIdx.x, tid = threadIdx.x;
    __shared__ float pl[128], mid[128];
    if (tid < 128) pl[tid] = pooled[bq * 128 + tid] * (1.f / 2048.f);
    __syncthreads();
    if (tid < 128) {
        float s = bo[tid];
#pragma unroll 4
        for (int c = 0; c < 128; ++c) s += pl[c] * Wo[c * 128 + tid];
        mid[tid] = s;
    }
    __syncthreads();
    for (int j = tid; j < 512; j += 256) {
        float s = bout[j];
#pragma unroll 4
        for (int i = 0; i < 128; ++i) s += mid[i] * Wout[i * 512 + j];
        out[bq * 512 + j] = s;
    }
}

// ---------------------------------------------------------------------------
extern "C" void kernel_launch(void* const* d_in, const int* in_sizes, int n_in,
                              void* d_out, int out_size, void* d_ws, size_t ws_size,
                              hipStream_t stream) {
    (void)in_sizes; (void)n_in; (void)out_size; (void)ws_size;
    const float* ohlc = (const float*)d_in[0];
    const float* Wp   = (const float*)d_in[1];  const float* bp   = (const float*)d_in[2];
    const float* Wc1  = (const float*)d_in[3];  const float* bc1  = (const float*)d_in[4];
    const float* Wc2  = (const float*)d_in[5];  const float* bc2  = (const float*)d_in[6];
    const float* Wv1  = (const float*)d_in[7];  const float* bv1  = (const float*)d_in[8];
    const float* Wv2  = (const float*)d_in[9];  const float* bv2  = (const float*)d_in[10];
    const float* Ws1  = (const float*)d_in[11]; const float* bs1  = (const float*)d_in[12];
    const float* Ws2  = (const float*)d_in[13]; const float* bs2  = (const float*)d_in[14];
    const float* Wqkv = (const float*)d_in[15]; const float* bqkv = (const float*)d_in[16];
    const float* Wo   = (const float*)d_in[17]; const float* bo   = (const float*)d_in[18];
    const float* Wout = (const float*)d_in[19]; const float* bout = (const float*)d_in[20];
    float* out = (float*)d_out;
    char* ws = (char*)d_ws;

    const size_t MB8 = 8388608;
    unsigned short* feats = (unsigned short*)(ws);
    unsigned short* qg    = (unsigned short*)(ws + 1 * MB8);
    unsigned short* kg    = (unsigned short*)(ws + 2 * MB8);
    unsigned short* vt2   = (unsigned short*)(ws + 3 * MB8);
    float*          pooled = (float*)(ws + 4 * MB8);
    float*          qkmax  = (float*)(ws + 4 * MB8 + 8192);
    unsigned short* wc1t  = (unsigned short*)(ws + 4 * MB8 + 8192 + 512);
    unsigned short* wc2t  = wc1t + 8192;
    unsigned short* wv1t  = wc2t + 4096;
    unsigned short* wv2t  = wv1t + 4096;
    unsigned short* ws1t  = wv2t + 1024;
    unsigned short* ws2t  = ws1t + 4096;
    unsigned short* wqkvt = ws2t + 1024;

    prep_kernel<<<145, 256, 0, stream>>>(Wqkv, Wc1, Wc2, Wv1, Wv2, Ws1, Ws2,
                                         wqkvt, wc1t, wc2t, wv1t, wv2t, ws1t, ws2t,
                                         pooled, qkmax);
    fused_mlp<<<dim3(512, 3), 256, 0, stream>>>(ohlc, Wp, bp, wc1t, bc1, wc2t, bc2,
                                                wv1t, bv1, wv2t, bv2, ws1t, bs1, ws2t, bs2, feats);
    qkv_gemm<<<dim3(256, 3), 256, 0, stream>>>(feats, wqkvt, bqkv, qg, kg, vt2, qkmax);
    attn_kernel<<<512, 256, 0, stream>>>(qg, kg, vt2, qkmax, pooled);
    head_kernel<<<16, 256, 0, stream>>>(pooled, Wo, bo, Wout, bout, out);
}